// Round 1
// baseline (188.788 us; speedup 1.0000x reference)
//
#include <hip/hip_runtime.h>

#define HH 1024
#define WW 1024
#define NB 8
#define TY 16
#define NSTRIPS (HH / TY)            // 64
#define NCC_BLOCKS (NB * NSTRIPS)    // 512
#define SROWS 16
#define NROWS_S (NB * 2 * HH)        // 16384
#define SM_BLOCKS (NROWS_S / SROWS)  // 1024

// ---------- NCC helpers ----------

__device__ __forceinline__ void load_win(const float* __restrict__ row, int q, float w[12]) {
    const float4* r4 = (const float4*)row;
    float4 m = (q > 0) ? r4[q - 1] : float4{0.f, 0.f, 0.f, 0.f};
    float4 c = r4[q];
    float4 p = (q < WW / 4 - 1) ? r4[q + 1] : float4{0.f, 0.f, 0.f, 0.f};
    w[0] = m.x; w[1] = m.y; w[2] = m.z; w[3] = m.w;
    w[4] = c.x; w[5] = c.y; w[6] = c.z; w[7] = c.w;
    w[8] = p.x; w[9] = p.y; w[10] = p.z; w[11] = p.w;
}

// Add (or subtract) the horizontal 9-sums of row y for 4 columns into the
// running vertical sums. Zero-padded rows (y OOB) contribute nothing.
// FMA form: no a2/b2/ab temporaries (saves ~36 VGPRs + ~30 VALU inst/row).
template <bool ADD>
__device__ __forceinline__ void accum_row(const float* __restrict__ Ib, const float* __restrict__ Jb,
                                          int y, int q,
                                          float vsI[4], float vsJ[4],
                                          float vsI2[4], float vsJ2[4], float vsIJ[4]) {
    if (y < 0 || y >= HH) return;   // block-uniform branch (y depends only on blockIdx/iter)
    float wI[12], wJ[12];
    load_win(Ib + (size_t)y * WW, q, wI);
    load_win(Jb + (size_t)y * WW, q, wJ);

    // linear 9-sums as balanced trees (FP adds are not reassociable by the compiler)
    float sI = (((wI[0] + wI[1]) + (wI[2] + wI[3])) + ((wI[4] + wI[5]) + (wI[6] + wI[7]))) + wI[8];
    float sJ = (((wJ[0] + wJ[1]) + (wJ[2] + wJ[3])) + ((wJ[4] + wJ[5]) + (wJ[6] + wJ[7]))) + wJ[8];

    // product 9-sums via FMA, two partial accumulators each for ILP
    float s2Ia = wI[0] * wI[0], s2Ib = wI[1] * wI[1];
    float s2Ja = wJ[0] * wJ[0], s2Jb = wJ[1] * wJ[1];
    float sIJa = wI[0] * wJ[0], sIJb = wI[1] * wJ[1];
#pragma unroll
    for (int k = 2; k < 9; k += 2) {
        s2Ia = fmaf(wI[k], wI[k], s2Ia);
        s2Ja = fmaf(wJ[k], wJ[k], s2Ja);
        sIJa = fmaf(wI[k], wJ[k], sIJa);
        if (k + 1 < 9) {
            s2Ib = fmaf(wI[k + 1], wI[k + 1], s2Ib);
            s2Jb = fmaf(wJ[k + 1], wJ[k + 1], s2Jb);
            sIJb = fmaf(wI[k + 1], wJ[k + 1], sIJb);
        }
    }
    float s2I = s2Ia + s2Ib;
    float s2J = s2Ja + s2Jb;
    float sIJ = sIJa + sIJb;

#pragma unroll
    for (int c = 0; c < 4; ++c) {
        if (c > 0) {
            sI += wI[c + 8] - wI[c - 1];
            sJ += wJ[c + 8] - wJ[c - 1];
            s2I = fmaf(wI[c + 8], wI[c + 8], fmaf(-wI[c - 1], wI[c - 1], s2I));
            s2J = fmaf(wJ[c + 8], wJ[c + 8], fmaf(-wJ[c - 1], wJ[c - 1], s2J));
            sIJ = fmaf(wI[c + 8], wJ[c + 8], fmaf(-wI[c - 1], wJ[c - 1], sIJ));
        }
        if (ADD) { vsI[c] += sI; vsJ[c] += sJ; vsI2[c] += s2I; vsJ2[c] += s2J; vsIJ[c] += sIJ; }
        else     { vsI[c] -= sI; vsJ[c] -= sJ; vsI2[c] -= s2I; vsJ2[c] -= s2J; vsIJ[c] -= sIJ; }
    }
}

// ---------- fused main kernel ----------
// Blocks [0, NCC_BLOCKS): NCC partial sums -> ws[bid]
// Blocks [NCC_BLOCKS, NCC_BLOCKS+SM_BLOCKS): smoothness partials -> ws[512+sb], ws[1536+sb]

__global__ __launch_bounds__(256) void fused_kernel(const float* __restrict__ I,
                                                    const float* __restrict__ J,
                                                    const float* __restrict__ S,
                                                    float* __restrict__ ws) {
    __shared__ float red[8];
    const int bid = blockIdx.x;
    const int t = threadIdx.x;
    const int lane = t & 63;
    const int wid = t >> 6;

    if (bid < NCC_BLOCKS) {
        const int b = bid >> 6;          // image index
        const int strip = bid & 63;      // row strip
        const int y0 = strip * TY;
        const int q = t;                 // float4 column index; x0 = 4*t
        const float* Ib = I + (size_t)b * HH * WW;
        const float* Jb = J + (size_t)b * HH * WW;

        float vsI[4] = {0.f, 0.f, 0.f, 0.f};
        float vsJ[4] = {0.f, 0.f, 0.f, 0.f};
        float vsI2[4] = {0.f, 0.f, 0.f, 0.f};
        float vsJ2[4] = {0.f, 0.f, 0.f, 0.f};
        float vsIJ[4] = {0.f, 0.f, 0.f, 0.f};
        float ccacc = 0.f;

        // warm-up: rows y0-4 .. y0+3
#pragma unroll 2
        for (int k = 0; k < 8; ++k)
            accum_row<true>(Ib, Jb, y0 - 4 + k, q, vsI, vsJ, vsI2, vsJ2, vsIJ);

        constexpr float RW = 1.0f / 81.0f;
#pragma unroll 2
        for (int k = 0; k < TY; ++k) {
            const int y = y0 + k;
            accum_row<true>(Ib, Jb, y + 4, q, vsI, vsJ, vsI2, vsJ2, vsIJ);
            // emit cc for row y, 4 columns (VS == sum of hsums rows y-4..y+4)
            // Algebraic identity: cross = IJ_sum - Is*Js/81, Iv = I2_sum - Is^2/81,
            // Jv = J2_sum - Js^2/81 (exactly equal to the reference's expansion).
#pragma unroll
            for (int c = 0; c < 4; ++c) {
                const float Is = vsI[c], Js = vsJ[c];
                const float aI = Is * RW;
                const float aJ = Js * RW;
                const float cross = fmaf(-aI, Js, vsIJ[c]);
                const float Iv = fmaf(-aI, Is, vsI2[c]);
                const float Jv = fmaf(-aJ, Js, vsJ2[c]);
                const float den = fmaf(Iv, Jv, 1e-9f);
                float r = __builtin_amdgcn_rcpf(den);
                r = r * fmaf(-den, r, 2.0f);          // one Newton step: rel err ~2^-28
                ccacc = fmaf(cross * cross, r, ccacc);
            }
            accum_row<false>(Ib, Jb, y - 4, q, vsI, vsJ, vsI2, vsJ2, vsIJ);
        }

#pragma unroll
        for (int o = 32; o; o >>= 1) ccacc += __shfl_down(ccacc, o);
        if (lane == 0) red[wid] = ccacc;
        __syncthreads();
        if (t == 0) ws[bid] = red[0] + red[1] + red[2] + red[3];
    } else {
        const int sb = bid - NCC_BLOCKS;
        const int r0 = sb * SROWS;                      // flat row in [0, 16384)
        const float* base = S + (size_t)r0 * WW;
        float dxacc = 0.f, dyacc = 0.f;

        float4 v = ((const float4*)base)[t];
#pragma unroll 2
        for (int k = 0; k < SROWS; ++k) {
            const int y = (r0 + k) & (HH - 1);          // row within channel image
            const float* rp = base + (size_t)k * WW;
            float d0 = v.y - v.x, d1 = v.z - v.y, d2 = v.w - v.z;
            dxacc += d0 * d0 + d1 * d1 + d2 * d2;
            if (t < 255) { const float vr = rp[4 * t + 4]; const float d3 = vr - v.w; dxacc += d3 * d3; }
            if (y < HH - 1) {
                const float4 vn = ((const float4*)(rp + WW))[t];
                const float e0 = vn.x - v.x, e1 = vn.y - v.y, e2 = vn.z - v.z, e3 = vn.w - v.w;
                dyacc += e0 * e0 + e1 * e1 + e2 * e2 + e3 * e3;
                v = vn;                                  // carry next row's data
            }
            // y==1023 only happens at k==SROWS-1 (blocks aligned to channel), no reload needed
        }

#pragma unroll
        for (int o = 32; o; o >>= 1) {
            dxacc += __shfl_down(dxacc, o);
            dyacc += __shfl_down(dyacc, o);
        }
        if (lane == 0) { red[wid] = dxacc; red[4 + wid] = dyacc; }
        __syncthreads();
        if (t == 0) {
            ws[NCC_BLOCKS + sb] = red[0] + red[1] + red[2] + red[3];
            ws[NCC_BLOCKS + SM_BLOCKS + sb] = red[4] + red[5] + red[6] + red[7];
        }
    }
}

// ---------- finalize ----------

__global__ __launch_bounds__(256) void finalize_kernel(const float* __restrict__ ws,
                                                       float* __restrict__ out) {
    __shared__ double sd[256];
    __shared__ double res[3];
    const int t = threadIdx.x;
    double cc = 0.0, dx = 0.0, dy = 0.0;
    for (int i = t; i < NCC_BLOCKS; i += 256) cc += (double)ws[i];
    for (int i = t; i < SM_BLOCKS; i += 256) dx += (double)ws[NCC_BLOCKS + i];
    for (int i = t; i < SM_BLOCKS; i += 256) dy += (double)ws[NCC_BLOCKS + SM_BLOCKS + i];

    sd[t] = cc; __syncthreads();
    for (int s = 128; s; s >>= 1) { if (t < s) sd[t] += sd[t + s]; __syncthreads(); }
    if (t == 0) res[0] = sd[0];
    __syncthreads();
    sd[t] = dx; __syncthreads();
    for (int s = 128; s; s >>= 1) { if (t < s) sd[t] += sd[t + s]; __syncthreads(); }
    if (t == 0) res[1] = sd[0];
    __syncthreads();
    sd[t] = dy; __syncthreads();
    for (int s = 128; s; s >>= 1) { if (t < s) sd[t] += sd[t + s]; __syncthreads(); }
    if (t == 0) {
        res[2] = sd[0];
        const double ncc = -(res[0] / ((double)NB * 1.0 * HH * WW));
        const double mdx = res[1] / ((double)NB * 2.0 * HH * (WW - 1));
        const double mdy = res[2] / ((double)NB * 2.0 * (HH - 1) * WW);
        const double smooth = 0.01 * 0.5 * (mdx + mdy);
        out[0] = (float)(ncc + smooth);
        out[1] = (float)ncc;
        out[2] = (float)smooth;
    }
}

extern "C" void kernel_launch(void* const* d_in, const int* in_sizes, int n_in,
                              void* d_out, int out_size, void* d_ws, size_t ws_size,
                              hipStream_t stream) {
    const float* I = (const float*)d_in[0];
    const float* J = (const float*)d_in[1];
    const float* S = (const float*)d_in[2];
    // d_in[3] = sum_filt (all-ones 9x9 box) — baked into the algorithm.
    float* ws = (float*)d_ws;     // 2560 float partials (10 KB)
    float* out = (float*)d_out;   // 3 floats: total, ncc, smooth

    fused_kernel<<<NCC_BLOCKS + SM_BLOCKS, 256, 0, stream>>>(I, J, S, ws);
    finalize_kernel<<<1, 256, 0, stream>>>(ws, out);
}

// Round 2
// 183.628 us; speedup vs baseline: 1.0281x; 1.0281x over previous
//
#include <hip/hip_runtime.h>

#define HH 1024
#define WW 1024
#define NB 8
#define TY 8
#define NSTRIPS (HH / TY)            // 128
#define NCC_BLOCKS (NB * NSTRIPS)    // 1024
#define SROWS 16
#define NROWS_S (NB * 2 * HH)        // 16384
#define SM_BLOCKS (NROWS_S / SROWS)  // 1024

// ---------- NCC helpers ----------

__device__ __forceinline__ void load_win(const float* __restrict__ row, int q, float w[12]) {
    const float4* r4 = (const float4*)row;
    float4 m = (q > 0) ? r4[q - 1] : float4{0.f, 0.f, 0.f, 0.f};
    float4 c = r4[q];
    float4 p = (q < WW / 4 - 1) ? r4[q + 1] : float4{0.f, 0.f, 0.f, 0.f};
    w[0] = m.x; w[1] = m.y; w[2] = m.z; w[3] = m.w;
    w[4] = c.x; w[5] = c.y; w[6] = c.z; w[7] = c.w;
    w[8] = p.x; w[9] = p.y; w[10] = p.z; w[11] = p.w;
}

// Accumulate (or subtract) the horizontal 9-sums of a pre-loaded row window
// into the running vertical sums. Pure register math — no loads.
template <bool ADD>
__device__ __forceinline__ void accum_regs(const float wI[12], const float wJ[12],
                                           float vsI[4], float vsJ[4],
                                           float vsI2[4], float vsJ2[4], float vsIJ[4]) {
    float sI = (((wI[0] + wI[1]) + (wI[2] + wI[3])) + ((wI[4] + wI[5]) + (wI[6] + wI[7]))) + wI[8];
    float sJ = (((wJ[0] + wJ[1]) + (wJ[2] + wJ[3])) + ((wJ[4] + wJ[5]) + (wJ[6] + wJ[7]))) + wJ[8];

    float s2Ia = wI[0] * wI[0], s2Ib = wI[1] * wI[1];
    float s2Ja = wJ[0] * wJ[0], s2Jb = wJ[1] * wJ[1];
    float sIJa = wI[0] * wJ[0], sIJb = wI[1] * wJ[1];
#pragma unroll
    for (int k = 2; k < 9; k += 2) {
        s2Ia = fmaf(wI[k], wI[k], s2Ia);
        s2Ja = fmaf(wJ[k], wJ[k], s2Ja);
        sIJa = fmaf(wI[k], wJ[k], sIJa);
        if (k + 1 < 9) {
            s2Ib = fmaf(wI[k + 1], wI[k + 1], s2Ib);
            s2Jb = fmaf(wJ[k + 1], wJ[k + 1], s2Jb);
            sIJb = fmaf(wI[k + 1], wJ[k + 1], sIJb);
        }
    }
    float s2I = s2Ia + s2Ib;
    float s2J = s2Ja + s2Jb;
    float sIJ = sIJa + sIJb;

#pragma unroll
    for (int c = 0; c < 4; ++c) {
        if (c > 0) {
            sI += wI[c + 8] - wI[c - 1];
            sJ += wJ[c + 8] - wJ[c - 1];
            s2I = fmaf(wI[c + 8], wI[c + 8], fmaf(-wI[c - 1], wI[c - 1], s2I));
            s2J = fmaf(wJ[c + 8], wJ[c + 8], fmaf(-wJ[c - 1], wJ[c - 1], s2J));
            sIJ = fmaf(wI[c + 8], wJ[c + 8], fmaf(-wI[c - 1], wJ[c - 1], sIJ));
        }
        if (ADD) { vsI[c] += sI; vsJ[c] += sJ; vsI2[c] += s2I; vsJ2[c] += s2J; vsIJ[c] += sIJ; }
        else     { vsI[c] -= sI; vsJ[c] -= sJ; vsI2[c] -= s2I; vsJ2[c] -= s2J; vsIJ[c] -= sIJ; }
    }
}

template <bool ADD>
__device__ __forceinline__ void accum_row(const float* __restrict__ Ib, const float* __restrict__ Jb,
                                          int y, int q,
                                          float vsI[4], float vsJ[4],
                                          float vsI2[4], float vsJ2[4], float vsIJ[4]) {
    if (y < 0 || y >= HH) return;   // block-uniform branch
    float wI[12], wJ[12];
    load_win(Ib + (size_t)y * WW, q, wI);
    load_win(Jb + (size_t)y * WW, q, wJ);
    accum_regs<ADD>(wI, wJ, vsI, vsJ, vsI2, vsJ2, vsIJ);
}

// ---------- fused main kernel ----------
// Blocks [0, NCC_BLOCKS): NCC partial sums -> ws[bid]
// Blocks [NCC_BLOCKS, NCC_BLOCKS+SM_BLOCKS): smoothness partials
//   -> ws[NCC_BLOCKS+sb] (dx), ws[NCC_BLOCKS+SM_BLOCKS+sb] (dy)

__global__ __launch_bounds__(256) void fused_kernel(const float* __restrict__ I,
                                                    const float* __restrict__ J,
                                                    const float* __restrict__ S,
                                                    float* __restrict__ ws) {
    __shared__ float red[8];
    const int bid = blockIdx.x;
    const int t = threadIdx.x;
    const int lane = t & 63;
    const int wid = t >> 6;

    if (bid < NCC_BLOCKS) {
        const int b = bid >> 7;          // image index (128 strips/image)
        const int strip = bid & 127;     // row strip
        const int y0 = strip * TY;
        const int q = t;                 // float4 column index; x0 = 4*t
        const float* Ib = I + (size_t)b * HH * WW;
        const float* Jb = J + (size_t)b * HH * WW;

        float vsI[4] = {0.f, 0.f, 0.f, 0.f};
        float vsJ[4] = {0.f, 0.f, 0.f, 0.f};
        float vsI2[4] = {0.f, 0.f, 0.f, 0.f};
        float vsJ2[4] = {0.f, 0.f, 0.f, 0.f};
        float vsIJ[4] = {0.f, 0.f, 0.f, 0.f};
        float ccacc = 0.f;

        // warm-up: rows y0-4 .. y0+3
#pragma unroll 2
        for (int k = 0; k < 8; ++k)
            accum_row<true>(Ib, Jb, y0 - 4 + k, q, vsI, vsJ, vsI2, vsJ2, vsIJ);

        constexpr float RW = 1.0f / 81.0f;
#pragma unroll 2
        for (int k = 0; k < TY; ++k) {
            const int y = y0 + k;
            const int ya = y + 4;        // row entering the vertical window
            const int yr = y - 4;        // row leaving it (after this emit)
            const bool va = (ya < HH);   // block-uniform
            const bool vr = (yr >= 0);   // block-uniform

            // Issue ALL loads for this iteration up front: 2x the in-flight
            // memory ops per wave (latency-bound regime — this is the lever).
            float wIa[12], wJa[12], wIr[12], wJr[12];
            if (va) { load_win(Ib + (size_t)ya * WW, q, wIa); load_win(Jb + (size_t)ya * WW, q, wJa); }
            if (vr) { load_win(Ib + (size_t)yr * WW, q, wIr); load_win(Jb + (size_t)yr * WW, q, wJr); }

            if (va) accum_regs<true>(wIa, wJa, vsI, vsJ, vsI2, vsJ2, vsIJ);

            // emit cc for row y (VS == sum of hsums rows y-4..y+4)
            // cross = IJ_sum - Is*Js/81, Iv = I2_sum - Is^2/81, Jv = J2_sum - Js^2/81
#pragma unroll
            for (int c = 0; c < 4; ++c) {
                const float Is = vsI[c], Js = vsJ[c];
                const float aI = Is * RW;
                const float aJ = Js * RW;
                const float cross = fmaf(-aI, Js, vsIJ[c]);
                const float Iv = fmaf(-aI, Is, vsI2[c]);
                const float Jv = fmaf(-aJ, Js, vsJ2[c]);
                const float den = fmaf(Iv, Jv, 1e-9f);
                float r = __builtin_amdgcn_rcpf(den);
                r = r * fmaf(-den, r, 2.0f);          // one Newton step: rel err ~2^-28
                ccacc = fmaf(cross * cross, r, ccacc);
            }

            if (vr) accum_regs<false>(wIr, wJr, vsI, vsJ, vsI2, vsJ2, vsIJ);
        }

#pragma unroll
        for (int o = 32; o; o >>= 1) ccacc += __shfl_down(ccacc, o);
        if (lane == 0) red[wid] = ccacc;
        __syncthreads();
        if (t == 0) ws[bid] = red[0] + red[1] + red[2] + red[3];
    } else {
        const int sb = bid - NCC_BLOCKS;
        const int r0 = sb * SROWS;                      // flat row in [0, 16384)
        const float* base = S + (size_t)r0 * WW;
        float dxacc = 0.f, dyacc = 0.f;

        float4 v = ((const float4*)base)[t];
#pragma unroll 2
        for (int k = 0; k < SROWS; ++k) {
            const int y = (r0 + k) & (HH - 1);          // row within channel image
            const float* rp = base + (size_t)k * WW;
            float d0 = v.y - v.x, d1 = v.z - v.y, d2 = v.w - v.z;
            dxacc += d0 * d0 + d1 * d1 + d2 * d2;
            if (t < 255) { const float vr = rp[4 * t + 4]; const float d3 = vr - v.w; dxacc += d3 * d3; }
            if (y < HH - 1) {
                const float4 vn = ((const float4*)(rp + WW))[t];
                const float e0 = vn.x - v.x, e1 = vn.y - v.y, e2 = vn.z - v.z, e3 = vn.w - v.w;
                dyacc += e0 * e0 + e1 * e1 + e2 * e2 + e3 * e3;
                v = vn;                                  // carry next row's data
            }
        }

#pragma unroll
        for (int o = 32; o; o >>= 1) {
            dxacc += __shfl_down(dxacc, o);
            dyacc += __shfl_down(dyacc, o);
        }
        if (lane == 0) { red[wid] = dxacc; red[4 + wid] = dyacc; }
        __syncthreads();
        if (t == 0) {
            ws[NCC_BLOCKS + sb] = red[0] + red[1] + red[2] + red[3];
            ws[NCC_BLOCKS + SM_BLOCKS + sb] = red[4] + red[5] + red[6] + red[7];
        }
    }
}

// ---------- finalize ----------

__global__ __launch_bounds__(256) void finalize_kernel(const float* __restrict__ ws,
                                                       float* __restrict__ out) {
    __shared__ double sd[256];
    __shared__ double res[3];
    const int t = threadIdx.x;
    double cc = 0.0, dx = 0.0, dy = 0.0;
    for (int i = t; i < NCC_BLOCKS; i += 256) cc += (double)ws[i];
    for (int i = t; i < SM_BLOCKS; i += 256) dx += (double)ws[NCC_BLOCKS + i];
    for (int i = t; i < SM_BLOCKS; i += 256) dy += (double)ws[NCC_BLOCKS + SM_BLOCKS + i];

    sd[t] = cc; __syncthreads();
    for (int s = 128; s; s >>= 1) { if (t < s) sd[t] += sd[t + s]; __syncthreads(); }
    if (t == 0) res[0] = sd[0];
    __syncthreads();
    sd[t] = dx; __syncthreads();
    for (int s = 128; s; s >>= 1) { if (t < s) sd[t] += sd[t + s]; __syncthreads(); }
    if (t == 0) res[1] = sd[0];
    __syncthreads();
    sd[t] = dy; __syncthreads();
    for (int s = 128; s; s >>= 1) { if (t < s) sd[t] += sd[t + s]; __syncthreads(); }
    if (t == 0) {
        res[2] = sd[0];
        const double ncc = -(res[0] / ((double)NB * 1.0 * HH * WW));
        const double mdx = res[1] / ((double)NB * 2.0 * HH * (WW - 1));
        const double mdy = res[2] / ((double)NB * 2.0 * (HH - 1) * WW);
        const double smooth = 0.01 * 0.5 * (mdx + mdy);
        out[0] = (float)(ncc + smooth);
        out[1] = (float)ncc;
        out[2] = (float)smooth;
    }
}

extern "C" void kernel_launch(void* const* d_in, const int* in_sizes, int n_in,
                              void* d_out, int out_size, void* d_ws, size_t ws_size,
                              hipStream_t stream) {
    const float* I = (const float*)d_in[0];
    const float* J = (const float*)d_in[1];
    const float* S = (const float*)d_in[2];
    // d_in[3] = sum_filt (all-ones 9x9 box) — baked into the algorithm.
    float* ws = (float*)d_ws;     // 3072 float partials (12 KB)
    float* out = (float*)d_out;   // 3 floats: total, ncc, smooth

    fused_kernel<<<NCC_BLOCKS + SM_BLOCKS, 256, 0, stream>>>(I, J, S, ws);
    finalize_kernel<<<1, 256, 0, stream>>>(ws, out);
}